// Round 1
// baseline (1760.165 us; speedup 1.0000x reference)
//
#include <hip/hip_runtime.h>
#include <math.h>

#define D   1024
#define H   16
#define HD  64
#define SEQ 2048
#define LL  8
#define QKV_LD 3072
#define SCALE 0.125f

// ---------------------------------------------------------------------------
// GEMM: C[M,N] = A[M,K] @ W[N,K]^T + bias[N]
// 128x128 tile, BK=16, 256 threads, 8x8 per thread. Grid: (N/128, M/128).
// ---------------------------------------------------------------------------
__global__ __launch_bounds__(256) void gemm_bias_kernel(
    const float* __restrict__ A, const float* __restrict__ W,
    const float* __restrict__ bias, float* __restrict__ C,
    int K, int N)
{
    __shared__ float As[16 * 128];
    __shared__ float Bs[16 * 128];
    const int t  = threadIdx.x;
    const int tx = t & 15, ty = t >> 4;
    const int m0 = blockIdx.y * 128, n0 = blockIdx.x * 128;
    const int row = t >> 1;          // 0..127
    const int kh  = (t & 1) * 8;     // 0 or 8

    float acc[8][8];
#pragma unroll
    for (int i = 0; i < 8; i++)
#pragma unroll
        for (int j = 0; j < 8; j++) acc[i][j] = 0.f;

    const float* Ag = A + (size_t)(m0 + row) * K + kh;
    const float* Wg = W + (size_t)(n0 + row) * K + kh;

    for (int k0 = 0; k0 < K; k0 += 16) {
        float4 a0 = *(const float4*)(Ag + k0);
        float4 a1 = *(const float4*)(Ag + k0 + 4);
        float4 b0 = *(const float4*)(Wg + k0);
        float4 b1 = *(const float4*)(Wg + k0 + 4);
        // transposed stores: As[kk][m], Bs[kk][n]  (2-way bank alias only)
        As[(kh + 0) * 128 + row] = a0.x;
        As[(kh + 1) * 128 + row] = a0.y;
        As[(kh + 2) * 128 + row] = a0.z;
        As[(kh + 3) * 128 + row] = a0.w;
        As[(kh + 4) * 128 + row] = a1.x;
        As[(kh + 5) * 128 + row] = a1.y;
        As[(kh + 6) * 128 + row] = a1.z;
        As[(kh + 7) * 128 + row] = a1.w;
        Bs[(kh + 0) * 128 + row] = b0.x;
        Bs[(kh + 1) * 128 + row] = b0.y;
        Bs[(kh + 2) * 128 + row] = b0.z;
        Bs[(kh + 3) * 128 + row] = b0.w;
        Bs[(kh + 4) * 128 + row] = b1.x;
        Bs[(kh + 5) * 128 + row] = b1.y;
        Bs[(kh + 6) * 128 + row] = b1.z;
        Bs[(kh + 7) * 128 + row] = b1.w;
        __syncthreads();
#pragma unroll
        for (int kk = 0; kk < 16; kk++) {
            float a[8], b[8];
            *(float4*)&a[0] = *(const float4*)&As[kk * 128 + ty * 8];
            *(float4*)&a[4] = *(const float4*)&As[kk * 128 + ty * 8 + 4];
            *(float4*)&b[0] = *(const float4*)&Bs[kk * 128 + tx * 8];
            *(float4*)&b[4] = *(const float4*)&Bs[kk * 128 + tx * 8 + 4];
#pragma unroll
            for (int i = 0; i < 8; i++)
#pragma unroll
                for (int j = 0; j < 8; j++)
                    acc[i][j] = fmaf(a[i], b[j], acc[i][j]);
        }
        __syncthreads();
    }

    float bb[8];
    *(float4*)&bb[0] = *(const float4*)&bias[n0 + tx * 8];
    *(float4*)&bb[4] = *(const float4*)&bias[n0 + tx * 8 + 4];
#pragma unroll
    for (int i = 0; i < 8; i++) {
        float* Crow = C + (size_t)(m0 + ty * 8 + i) * N + n0 + tx * 8;
        float4 c0, c1;
        c0.x = acc[i][0] + bb[0]; c0.y = acc[i][1] + bb[1];
        c0.z = acc[i][2] + bb[2]; c0.w = acc[i][3] + bb[3];
        c1.x = acc[i][4] + bb[4]; c1.y = acc[i][5] + bb[5];
        c1.z = acc[i][6] + bb[6]; c1.w = acc[i][7] + bb[7];
        *(float4*)(Crow)     = c0;
        *(float4*)(Crow + 4) = c1;
    }
}

// ---------------------------------------------------------------------------
// LayerNorm of reprojected past_values.
// ri[s*L + l, h*64 + e] = LN(past_values[l, 0, h, s, e]) over d=1024.
// One block (256 thr) per row; thread t handles 4 contiguous cols.
// ---------------------------------------------------------------------------
__global__ __launch_bounds__(256) void ln_kernel(
    const float* __restrict__ pv, float* __restrict__ ri)
{
    const int r = blockIdx.x;
    const int s = r >> 3, l = r & 7;
    const int t = threadIdx.x;
    const int h = t >> 4, e = (t & 15) * 4;
    const size_t src = (size_t)l * (H * SEQ * HD) + (size_t)h * (SEQ * HD)
                     + (size_t)s * HD + e;
    float4 v = *(const float4*)(pv + src);
    float sum = v.x + v.y + v.z + v.w;
    float sq  = v.x * v.x + v.y * v.y + v.z * v.z + v.w * v.w;
#pragma unroll
    for (int off = 32; off; off >>= 1) {
        sum += __shfl_xor(sum, off);
        sq  += __shfl_xor(sq, off);
    }
    __shared__ float red[8];
    if ((t & 63) == 0) { red[(t >> 6) * 2] = sum; red[(t >> 6) * 2 + 1] = sq; }
    __syncthreads();
    sum = red[0] + red[2] + red[4] + red[6];
    sq  = red[1] + red[3] + red[5] + red[7];
    const float mean = sum * (1.f / 1024.f);
    const float var  = sq * (1.f / 1024.f) - mean * mean;
    const float rstd = rsqrtf(var + 1e-5f);
    float4 o;
    o.x = (v.x - mean) * rstd; o.y = (v.y - mean) * rstd;
    o.z = (v.z - mean) * rstd; o.w = (v.w - mean) * rstd;
    *(float4*)(ri + (size_t)r * D + t * 4) = o;
}

// ---------------------------------------------------------------------------
// Flash-style dual attention.
// Block = (head h, 64-query tile). 256 threads, tx=t&15, ty=t>>4.
// Token keys: causal flash loop over 64-key tiles.
// Memory keys: 8 per query from rkv (cols 0..1023 = rk, 1024..2047 = rv),
// folded into the online softmax in the epilogue.
// ---------------------------------------------------------------------------
__global__ __launch_bounds__(256) void attn_kernel(
    const float* __restrict__ qkv, const float* __restrict__ qcol,
    const float* __restrict__ rkv, float* __restrict__ ctx)
{
    const int t  = threadIdx.x;
    const int tx = t & 15, ty = t >> 4;
    const int h  = blockIdx.y;
    const int qt = blockIdx.x;
    const int q0 = qt * 64;

    __shared__ float Qs[64 * 64];   // [e][qi], pre-scaled
    __shared__ float KV[64 * 64];   // K phase: [e][j]; V phase: [j][e]
    __shared__ float Ps[64 * 64];   // [qi][j]
    __shared__ float row_m[64];
    __shared__ float mem_alpha[64];
    __shared__ float mem_suml[64];
    __shared__ float mem_p[64 * 8];

    // Load Q (scaled) into Qs[e][qi]
    for (int idx = t; idx < 1024; idx += 256) {
        const int qi = idx & 63, ec = (idx >> 6) << 2;
        float4 v = *(const float4*)(qkv + (size_t)(q0 + qi) * QKV_LD + h * HD + ec);
        Qs[(ec + 0) * 64 + qi] = v.x * SCALE;
        Qs[(ec + 1) * 64 + qi] = v.y * SCALE;
        Qs[(ec + 2) * 64 + qi] = v.z * SCALE;
        Qs[(ec + 3) * 64 + qi] = v.w * SCALE;
    }
    float m_i[4], l_i[4], O[4][4];
#pragma unroll
    for (int i = 0; i < 4; i++) {
        m_i[i] = -1e30f; l_i[i] = 0.f;
#pragma unroll
        for (int j = 0; j < 4; j++) O[i][j] = 0.f;
    }
    __syncthreads();

    for (int jt = 0; jt <= qt; ++jt) {
        const int j0 = jt * 64;
        // K tile -> KV[e][j]
        for (int idx = t; idx < 1024; idx += 256) {
            const int j = idx & 63, ec = (idx >> 6) << 2;
            float4 v = *(const float4*)(qkv + (size_t)(j0 + j) * QKV_LD + D + h * HD + ec);
            KV[(ec + 0) * 64 + j] = v.x;
            KV[(ec + 1) * 64 + j] = v.y;
            KV[(ec + 2) * 64 + j] = v.z;
            KV[(ec + 3) * 64 + j] = v.w;
        }
        __syncthreads();

        float Sc[4][4];
#pragma unroll
        for (int i = 0; i < 4; i++)
#pragma unroll
            for (int j = 0; j < 4; j++) Sc[i][j] = 0.f;
        for (int e = 0; e < 64; e++) {
            float a[4], b[4];
            *(float4*)a = *(const float4*)&Qs[e * 64 + ty * 4];
            *(float4*)b = *(const float4*)&KV[e * 64 + tx * 4];
#pragma unroll
            for (int i = 0; i < 4; i++)
#pragma unroll
                for (int j = 0; j < 4; j++)
                    Sc[i][j] = fmaf(a[i], b[j], Sc[i][j]);
        }

        // mask + online softmax update; write P (row-major [qi][j])
#pragma unroll
        for (int i = 0; i < 4; i++) {
            const int qg = q0 + ty * 4 + i;
            float mx = -1e30f;
#pragma unroll
            for (int j = 0; j < 4; j++) {
                const int jg = j0 + tx * 4 + j;
                if (jg > qg) Sc[i][j] = -1e30f;
                mx = fmaxf(mx, Sc[i][j]);
            }
#pragma unroll
            for (int off = 1; off < 16; off <<= 1)
                mx = fmaxf(mx, __shfl_xor(mx, off));
            const float newm  = fmaxf(m_i[i], mx);
            const float alpha = __expf(m_i[i] - newm);
            m_i[i] = newm;
            float4 p;
            p.x = __expf(Sc[i][0] - newm);
            p.y = __expf(Sc[i][1] - newm);
            p.z = __expf(Sc[i][2] - newm);
            p.w = __expf(Sc[i][3] - newm);
            *(float4*)&Ps[(ty * 4 + i) * 64 + tx * 4] = p;
            float ps = p.x + p.y + p.z + p.w;
#pragma unroll
            for (int off = 1; off < 16; off <<= 1)
                ps += __shfl_xor(ps, off);
            l_i[i] = l_i[i] * alpha + ps;
#pragma unroll
            for (int j = 0; j < 4; j++) O[i][j] *= alpha;
        }
        __syncthreads();   // done reading K, done writing Ps

        // V tile -> KV[j][e]
        for (int idx = t; idx < 1024; idx += 256) {
            const int j = idx >> 4, ec = (idx & 15) << 2;
            float4 v = *(const float4*)(qkv + (size_t)(j0 + j) * QKV_LD + 2 * D + h * HD + ec);
            *(float4*)&KV[j * 64 + ec] = v;
        }
        __syncthreads();

        // O += P @ V
#pragma unroll 4
        for (int k4 = 0; k4 < 16; k4++) {
            float p[4][4], vv[4][4];
#pragma unroll
            for (int i = 0; i < 4; i++)
                *(float4*)p[i] = *(const float4*)&Ps[(ty * 4 + i) * 64 + k4 * 4];
#pragma unroll
            for (int kk = 0; kk < 4; kk++)
                *(float4*)vv[kk] = *(const float4*)&KV[(k4 * 4 + kk) * 64 + tx * 4];
#pragma unroll
            for (int i = 0; i < 4; i++)
#pragma unroll
                for (int kk = 0; kk < 4; kk++)
#pragma unroll
                    for (int j = 0; j < 4; j++)
                        O[i][j] = fmaf(p[i][kk], vv[kk][j], O[i][j]);
        }
        __syncthreads();
    }

    // ---- memory-key epilogue ----
    if (tx == 0) {
#pragma unroll
        for (int i = 0; i < 4; i++) row_m[ty * 4 + i] = m_i[i];
    }
    __syncthreads();
    {
        const int qi = t >> 2, quad = t & 3;
        const int qg = q0 + qi;
        float qv[16];
        const float* qcp = qcol + (size_t)qg * D + h * HD + quad * 16;
#pragma unroll
        for (int c = 0; c < 4; c++) {
            float4 v = *(const float4*)(qcp + c * 4);
            qv[c * 4 + 0] = v.x * SCALE; qv[c * 4 + 1] = v.y * SCALE;
            qv[c * 4 + 2] = v.z * SCALE; qv[c * 4 + 3] = v.w * SCALE;
        }
        float ms[8];
#pragma unroll
        for (int l = 0; l < 8; l++) {
            const float* rr = rkv + (size_t)(qg * LL + l) * 2048 + h * HD + quad * 16;
            float pacc = 0.f;
#pragma unroll
            for (int c = 0; c < 4; c++) {
                float4 v = *(const float4*)(rr + c * 4);
                pacc += qv[c * 4 + 0] * v.x + qv[c * 4 + 1] * v.y
                      + qv[c * 4 + 2] * v.z + qv[c * 4 + 3] * v.w;
            }
            pacc += __shfl_xor(pacc, 1);
            pacc += __shfl_xor(pacc, 2);
            ms[l] = pacc;
        }
        const float mo = row_m[qi];
        float mm = mo;
#pragma unroll
        for (int l = 0; l < 8; l++) mm = fmaxf(mm, ms[l]);
        const float alpha = __expf(mo - mm);
        float suml = 0.f;
        float pl[8];
#pragma unroll
        for (int l = 0; l < 8; l++) { pl[l] = __expf(ms[l] - mm); suml += pl[l]; }
        if (quad == 0) {
            mem_alpha[qi] = alpha;
            mem_suml[qi]  = suml;
#pragma unroll
            for (int l = 0; l < 8; l++) mem_p[qi * 8 + l] = pl[l];
        }
    }
    __syncthreads();

#pragma unroll
    for (int i = 0; i < 4; i++) {
        const int qi = ty * 4 + i, qg = q0 + qi;
        const float alpha = mem_alpha[qi];
        const float lf = l_i[i] * alpha + mem_suml[qi];
        float4 o;
        o.x = O[i][0] * alpha; o.y = O[i][1] * alpha;
        o.z = O[i][2] * alpha; o.w = O[i][3] * alpha;
#pragma unroll
        for (int l = 0; l < 8; l++) {
            const float p = mem_p[qi * 8 + l];
            float4 v = *(const float4*)(rkv + (size_t)(qg * LL + l) * 2048 + D + h * HD + tx * 4);
            o.x = fmaf(p, v.x, o.x); o.y = fmaf(p, v.y, o.y);
            o.z = fmaf(p, v.z, o.z); o.w = fmaf(p, v.w, o.w);
        }
        const float r = 1.f / lf;
        o.x *= r; o.y *= r; o.z *= r; o.w *= r;
        *(float4*)(ctx + (size_t)qg * D + h * HD + tx * 4) = o;
    }
}

// ---------------------------------------------------------------------------
extern "C" void kernel_launch(void* const* d_in, const int* in_sizes, int n_in,
                              void* d_out, int out_size, void* d_ws, size_t ws_size,
                              hipStream_t stream)
{
    const float* x    = (const float*)d_in[0];
    const float* pv   = (const float*)d_in[1];
    const float* Wqkv = (const float*)d_in[2];
    const float* bqkv = (const float*)d_in[3];
    const float* Wcol = (const float*)d_in[4];
    const float* bcol = (const float*)d_in[5];
    const float* Wout = (const float*)d_in[6];
    const float* bout = (const float*)d_in[7];
    float* out = (float*)d_out;

    float* ws    = (float*)d_ws;
    float* qkv   = ws;                       // 2048*3072  = 6291456
    float* qcolw = qkv   + 6291456;          // 2048*1024  = 2097152
    float* ri    = qcolw + 2097152;          // 16384*1024 = 16777216
    float* rkv   = ri    + 16777216;         // 16384*2048 = 33554432
    float* ctx   = rkv   + 33554432;         // 2048*1024  = 2097152
    // total 60,817,408 floats = 243.3 MB

    // qkv = x @ Wqkv^T + bqkv
    gemm_bias_kernel<<<dim3(24, 16), 256, 0, stream>>>(x, Wqkv, bqkv, qkv, 1024, 3072);
    // q_col = x @ Wcol^T + bcol
    gemm_bias_kernel<<<dim3(8, 16), 256, 0, stream>>>(x, Wcol, bcol, qcolw, 1024, 1024);
    // ri = LN(reproject(past_values))
    ln_kernel<<<16384, 256, 0, stream>>>(pv, ri);
    // rkv = ri @ Wqkv[1024:3072]^T + bqkv[1024:3072]   (rk cols 0..1023, rv 1024..2047)
    gemm_bias_kernel<<<dim3(16, 128), 256, 0, stream>>>(ri, Wqkv + 1024 * 1024, bqkv + 1024, rkv, 1024, 2048);
    // attention
    attn_kernel<<<dim3(32, 16), 256, 0, stream>>>(qkv, qcolw, rkv, ctx);
    // out = ctx @ Wout^T + bout
    gemm_bias_kernel<<<dim3(8, 16), 256, 0, stream>>>(ctx, Wout, bout, out, 1024, 1024);
}

// Round 2
// 611.068 us; speedup vs baseline: 2.8805x; 2.8805x over previous
//
#include <hip/hip_runtime.h>
#include <math.h>

#define D   1024
#define H   16
#define HD  64
#define SEQ 2048
#define LL  8
#define QKV_LD 3072
#define SCALE 0.125f

typedef __attribute__((ext_vector_type(8))) __bf16 bf16x8;
typedef __attribute__((ext_vector_type(4))) float floatx4;

__device__ inline unsigned short f32_to_bf16(float f) {
    unsigned int u = __builtin_bit_cast(unsigned int, f);
    u += 0x7FFF + ((u >> 16) & 1);   // round-to-nearest-even
    return (unsigned short)(u >> 16);
}

__device__ inline void load_lds16(const void* g, void* l) {
    __builtin_amdgcn_global_load_lds(
        (__attribute__((address_space(1))) void*)g,
        (__attribute__((address_space(3))) void*)l, 16, 0, 0);
}

// ---------------------------------------------------------------------------
// f32 -> bf16 convert (vectorized: 4 elems/thread)
// ---------------------------------------------------------------------------
__global__ __launch_bounds__(256) void cvt_bf16_kernel(
    const float* __restrict__ in, unsigned short* __restrict__ out, int n4)
{
    int i = blockIdx.x * 256 + threadIdx.x;
    if (i < n4) {
        float4 v = ((const float4*)in)[i];
        ushort4 o;
        o.x = f32_to_bf16(v.x); o.y = f32_to_bf16(v.y);
        o.z = f32_to_bf16(v.z); o.w = f32_to_bf16(v.w);
        ((ushort4*)out)[i] = o;
    }
}

// ---------------------------------------------------------------------------
// bf16 MFMA GEMM (m97 structure): C[M,N] = A[M,K] @ W[N,K]^T + bias[N]
// A, W bf16 row-major (K-major). 128x128 tile, BK=32, 256 threads (4 waves),
// each wave computes 64x64 via 4x4 grid of 16x16x32 MFMAs. f32 output.
// Grid: (N/128, M/128).
// ---------------------------------------------------------------------------
__global__ __launch_bounds__(256) void gemm_bf16_kernel(
    const unsigned short* __restrict__ A, const unsigned short* __restrict__ W,
    const float* __restrict__ bias, float* __restrict__ C, int K, int N)
{
    __shared__ unsigned short As[128 * 32];   // [m][k], 8 KB
    __shared__ unsigned short Ws[128 * 32];   // [n][k], 8 KB
    const int t    = threadIdx.x;
    const int wave = t >> 6, lane = t & 63;
    const int wm   = wave >> 1, wn = wave & 1;
    const int m0   = blockIdx.y * 128, n0 = blockIdx.x * 128;

    floatx4 acc[4][4];
#pragma unroll
    for (int i = 0; i < 4; i++)
#pragma unroll
        for (int j = 0; j < 4; j++) acc[i][j] = (floatx4)0.f;

    // staging addresses: wave w fills rows [w*32, w*32+32) of each tile,
    // two 1KB wave-DMAs per matrix (16 rows each); lane l -> row l/4, col (l&3)*8
    const int lrow = lane >> 2;
    const int lcol = (lane & 3) * 8;
    const unsigned short* Ag = A + (size_t)(m0 + wave * 32 + lrow) * K + lcol;
    const unsigned short* Wg = W + (size_t)(n0 + wave * 32 + lrow) * K + lcol;
    unsigned short* Asw = &As[wave * 32 * 32];
    unsigned short* Wsw = &Ws[wave * 32 * 32];
    const size_t rowskip = (size_t)16 * K;

    const int arow  = lane & 15;          // fragment row (m or n)
    const int aquad = (lane >> 4) * 8;    // fragment k-offset

    for (int k0 = 0; k0 < K; k0 += 32) {
        load_lds16(Ag + k0,           Asw);
        load_lds16(Ag + k0 + rowskip, Asw + 16 * 32);
        load_lds16(Wg + k0,           Wsw);
        load_lds16(Wg + k0 + rowskip, Wsw + 16 * 32);
        __syncthreads();   // vmcnt(0) drain + barrier

        bf16x8 af[4], wf[4];
#pragma unroll
        for (int mi = 0; mi < 4; mi++)
            af[mi] = *(const bf16x8*)&As[(wm * 64 + mi * 16 + arow) * 32 + aquad];
#pragma unroll
        for (int ni = 0; ni < 4; ni++)
            wf[ni] = *(const bf16x8*)&Ws[(wn * 64 + ni * 16 + arow) * 32 + aquad];
#pragma unroll
        for (int mi = 0; mi < 4; mi++)
#pragma unroll
            for (int ni = 0; ni < 4; ni++)
                acc[mi][ni] = __builtin_amdgcn_mfma_f32_16x16x32_bf16(
                    af[mi], wf[ni], acc[mi][ni], 0, 0, 0);
        __syncthreads();
    }

    // epilogue: C/D layout col=lane&15, row=(lane>>4)*4+reg
    const int crow = (lane >> 4) * 4, ccol = lane & 15;
#pragma unroll
    for (int mi = 0; mi < 4; mi++) {
#pragma unroll
        for (int ni = 0; ni < 4; ni++) {
            const int gm = m0 + wm * 64 + mi * 16 + crow;
            const int gn = n0 + wn * 64 + ni * 16 + ccol;
            const float bb = bias[gn];
#pragma unroll
            for (int r = 0; r < 4; r++)
                C[(size_t)(gm + r) * N + gn] = acc[mi][ni][r] + bb;
        }
    }
}

// ---------------------------------------------------------------------------
// LayerNorm of reprojected past_values -> bf16.
// ri[s*L + l, h*64 + e] = LN(past_values[l, 0, h, s, e]) over d=1024.
// ---------------------------------------------------------------------------
__global__ __launch_bounds__(256) void ln_kernel(
    const float* __restrict__ pv, unsigned short* __restrict__ ri)
{
    const int r = blockIdx.x;
    const int s = r >> 3, l = r & 7;
    const int t = threadIdx.x;
    const int h = t >> 4, e = (t & 15) * 4;
    const size_t src = (size_t)l * (H * SEQ * HD) + (size_t)h * (SEQ * HD)
                     + (size_t)s * HD + e;
    float4 v = *(const float4*)(pv + src);
    float sum = v.x + v.y + v.z + v.w;
    float sq  = v.x * v.x + v.y * v.y + v.z * v.z + v.w * v.w;
#pragma unroll
    for (int off = 32; off; off >>= 1) {
        sum += __shfl_xor(sum, off);
        sq  += __shfl_xor(sq, off);
    }
    __shared__ float red[8];
    if ((t & 63) == 0) { red[(t >> 6) * 2] = sum; red[(t >> 6) * 2 + 1] = sq; }
    __syncthreads();
    sum = red[0] + red[2] + red[4] + red[6];
    sq  = red[1] + red[3] + red[5] + red[7];
    const float mean = sum * (1.f / 1024.f);
    const float var  = sq * (1.f / 1024.f) - mean * mean;
    const float rstd = rsqrtf(var + 1e-5f);
    ushort4 o;
    o.x = f32_to_bf16((v.x - mean) * rstd);
    o.y = f32_to_bf16((v.y - mean) * rstd);
    o.z = f32_to_bf16((v.z - mean) * rstd);
    o.w = f32_to_bf16((v.w - mean) * rstd);
    *(ushort4*)(ri + (size_t)r * D + t * 4) = o;
}

// ---------------------------------------------------------------------------
// Flash-style dual attention (f32 VALU). Writes ctx as bf16.
// ---------------------------------------------------------------------------
__global__ __launch_bounds__(256) void attn_kernel(
    const float* __restrict__ qkv, const float* __restrict__ qcol,
    const float* __restrict__ rkv, unsigned short* __restrict__ ctx)
{
    const int t  = threadIdx.x;
    const int tx = t & 15, ty = t >> 4;
    const int h  = blockIdx.y;
    const int qt = blockIdx.x;
    const int q0 = qt * 64;

    __shared__ float Qs[64 * 64];   // [e][qi], pre-scaled
    __shared__ float KV[64 * 64];   // K phase: [e][j]; V phase: [j][e]
    __shared__ float Ps[64 * 64];   // [qi][j]
    __shared__ float row_m[64];
    __shared__ float mem_alpha[64];
    __shared__ float mem_suml[64];
    __shared__ float mem_p[64 * 8];

    for (int idx = t; idx < 1024; idx += 256) {
        const int qi = idx & 63, ec = (idx >> 6) << 2;
        float4 v = *(const float4*)(qkv + (size_t)(q0 + qi) * QKV_LD + h * HD + ec);
        Qs[(ec + 0) * 64 + qi] = v.x * SCALE;
        Qs[(ec + 1) * 64 + qi] = v.y * SCALE;
        Qs[(ec + 2) * 64 + qi] = v.z * SCALE;
        Qs[(ec + 3) * 64 + qi] = v.w * SCALE;
    }
    float m_i[4], l_i[4], O[4][4];
#pragma unroll
    for (int i = 0; i < 4; i++) {
        m_i[i] = -1e30f; l_i[i] = 0.f;
#pragma unroll
        for (int j = 0; j < 4; j++) O[i][j] = 0.f;
    }
    __syncthreads();

    for (int jt = 0; jt <= qt; ++jt) {
        const int j0 = jt * 64;
        for (int idx = t; idx < 1024; idx += 256) {
            const int j = idx & 63, ec = (idx >> 6) << 2;
            float4 v = *(const float4*)(qkv + (size_t)(j0 + j) * QKV_LD + D + h * HD + ec);
            KV[(ec + 0) * 64 + j] = v.x;
            KV[(ec + 1) * 64 + j] = v.y;
            KV[(ec + 2) * 64 + j] = v.z;
            KV[(ec + 3) * 64 + j] = v.w;
        }
        __syncthreads();

        float Sc[4][4];
#pragma unroll
        for (int i = 0; i < 4; i++)
#pragma unroll
            for (int j = 0; j < 4; j++) Sc[i][j] = 0.f;
        for (int e = 0; e < 64; e++) {
            float a[4], b[4];
            *(float4*)a = *(const float4*)&Qs[e * 64 + ty * 4];
            *(float4*)b = *(const float4*)&KV[e * 64 + tx * 4];
#pragma unroll
            for (int i = 0; i < 4; i++)
#pragma unroll
                for (int j = 0; j < 4; j++)
                    Sc[i][j] = fmaf(a[i], b[j], Sc[i][j]);
        }

#pragma unroll
        for (int i = 0; i < 4; i++) {
            const int qg = q0 + ty * 4 + i;
            float mx = -1e30f;
#pragma unroll
            for (int j = 0; j < 4; j++) {
                const int jg = j0 + tx * 4 + j;
                if (jg > qg) Sc[i][j] = -1e30f;
                mx = fmaxf(mx, Sc[i][j]);
            }
#pragma unroll
            for (int off = 1; off < 16; off <<= 1)
                mx = fmaxf(mx, __shfl_xor(mx, off));
            const float newm  = fmaxf(m_i[i], mx);
            const float alpha = __expf(m_i[i] - newm);
            m_i[i] = newm;
            float4 p;
            p.x = __expf(Sc[i][0] - newm);
            p.y = __expf(Sc[i][1] - newm);
            p.z = __expf(Sc[i][2] - newm);
            p.w = __expf(Sc[i][3] - newm);
            *(float4*)&Ps[(ty * 4 + i) * 64 + tx * 4] = p;
            float ps = p.x + p.y + p.z + p.w;
#pragma unroll
            for (int off = 1; off < 16; off <<= 1)
                ps += __shfl_xor(ps, off);
            l_i[i] = l_i[i] * alpha + ps;
#pragma unroll
            for (int j = 0; j < 4; j++) O[i][j] *= alpha;
        }
        __syncthreads();

        for (int idx = t; idx < 1024; idx += 256) {
            const int j = idx >> 4, ec = (idx & 15) << 2;
            float4 v = *(const float4*)(qkv + (size_t)(j0 + j) * QKV_LD + 2 * D + h * HD + ec);
            *(float4*)&KV[j * 64 + ec] = v;
        }
        __syncthreads();

#pragma unroll 4
        for (int k4 = 0; k4 < 16; k4++) {
            float p[4][4], vv[4][4];
#pragma unroll
            for (int i = 0; i < 4; i++)
                *(float4*)p[i] = *(const float4*)&Ps[(ty * 4 + i) * 64 + k4 * 4];
#pragma unroll
            for (int kk = 0; kk < 4; kk++)
                *(float4*)vv[kk] = *(const float4*)&KV[(k4 * 4 + kk) * 64 + tx * 4];
#pragma unroll
            for (int i = 0; i < 4; i++)
#pragma unroll
                for (int kk = 0; kk < 4; kk++)
#pragma unroll
                    for (int j = 0; j < 4; j++)
                        O[i][j] = fmaf(p[i][kk], vv[kk][j], O[i][j]);
        }
        __syncthreads();
    }

    if (tx == 0) {
#pragma unroll
        for (int i = 0; i < 4; i++) row_m[ty * 4 + i] = m_i[i];
    }
    __syncthreads();
    {
        const int qi = t >> 2, quad = t & 3;
        const int qg = q0 + qi;
        float qv[16];
        const float* qcp = qcol + (size_t)qg * D + h * HD + quad * 16;
#pragma unroll
        for (int c = 0; c < 4; c++) {
            float4 v = *(const float4*)(qcp + c * 4);
            qv[c * 4 + 0] = v.x * SCALE; qv[c * 4 + 1] = v.y * SCALE;
            qv[c * 4 + 2] = v.z * SCALE; qv[c * 4 + 3] = v.w * SCALE;
        }
        float ms[8];
#pragma unroll
        for (int l = 0; l < 8; l++) {
            const float* rr = rkv + (size_t)(qg * LL + l) * 2048 + h * HD + quad * 16;
            float pacc = 0.f;
#pragma unroll
            for (int c = 0; c < 4; c++) {
                float4 v = *(const float4*)(rr + c * 4);
                pacc += qv[c * 4 + 0] * v.x + qv[c * 4 + 1] * v.y
                      + qv[c * 4 + 2] * v.z + qv[c * 4 + 3] * v.w;
            }
            pacc += __shfl_xor(pacc, 1);
            pacc += __shfl_xor(pacc, 2);
            ms[l] = pacc;
        }
        const float mo = row_m[qi];
        float mm = mo;
#pragma unroll
        for (int l = 0; l < 8; l++) mm = fmaxf(mm, ms[l]);
        const float alpha = __expf(mo - mm);
        float suml = 0.f;
        float pl[8];
#pragma unroll
        for (int l = 0; l < 8; l++) { pl[l] = __expf(ms[l] - mm); suml += pl[l]; }
        if (quad == 0) {
            mem_alpha[qi] = alpha;
            mem_suml[qi]  = suml;
#pragma unroll
            for (int l = 0; l < 8; l++) mem_p[qi * 8 + l] = pl[l];
        }
    }
    __syncthreads();

#pragma unroll
    for (int i = 0; i < 4; i++) {
        const int qi = ty * 4 + i, qg = q0 + qi;
        const float alpha = mem_alpha[qi];
        const float lf = l_i[i] * alpha + mem_suml[qi];
        float4 o;
        o.x = O[i][0] * alpha; o.y = O[i][1] * alpha;
        o.z = O[i][2] * alpha; o.w = O[i][3] * alpha;
#pragma unroll
        for (int l = 0; l < 8; l++) {
            const float p = mem_p[qi * 8 + l];
            float4 v = *(const float4*)(rkv + (size_t)(qg * LL + l) * 2048 + D + h * HD + tx * 4);
            o.x = fmaf(p, v.x, o.x); o.y = fmaf(p, v.y, o.y);
            o.z = fmaf(p, v.z, o.z); o.w = fmaf(p, v.w, o.w);
        }
        const float r = 1.f / lf;
        ushort4 ob;
        ob.x = f32_to_bf16(o.x * r); ob.y = f32_to_bf16(o.y * r);
        ob.z = f32_to_bf16(o.z * r); ob.w = f32_to_bf16(o.w * r);
        *(ushort4*)(ctx + (size_t)qg * D + h * HD + tx * 4) = ob;
    }
}

// ---------------------------------------------------------------------------
extern "C" void kernel_launch(void* const* d_in, const int* in_sizes, int n_in,
                              void* d_out, int out_size, void* d_ws, size_t ws_size,
                              hipStream_t stream)
{
    const float* x    = (const float*)d_in[0];
    const float* pv   = (const float*)d_in[1];
    const float* Wqkv = (const float*)d_in[2];
    const float* bqkv = (const float*)d_in[3];
    const float* Wcol = (const float*)d_in[4];
    const float* bcol = (const float*)d_in[5];
    const float* Wout = (const float*)d_in[6];
    const float* bout = (const float*)d_in[7];
    float* out = (float*)d_out;

    char* p = (char*)d_ws;
    float* qkv   = (float*)p; p += (size_t)2048 * 3072 * 4;   // 25.2 MB
    float* qcolw = (float*)p; p += (size_t)2048 * 1024 * 4;   //  8.4 MB
    float* rkv   = (float*)p; p += (size_t)16384 * 2048 * 4;  // 134.2 MB
    unsigned short* x_bf    = (unsigned short*)p; p += (size_t)2048 * 1024 * 2;
    unsigned short* Wqkv_bf = (unsigned short*)p; p += (size_t)3072 * 1024 * 2;
    unsigned short* Wcol_bf = (unsigned short*)p; p += (size_t)1024 * 1024 * 2;
    unsigned short* Wout_bf = (unsigned short*)p; p += (size_t)1024 * 1024 * 2;
    unsigned short* ri_bf   = (unsigned short*)p; p += (size_t)16384 * 1024 * 2;
    unsigned short* ctx_bf  = (unsigned short*)p; p += (size_t)2048 * 1024 * 2;
    // total ~220 MB

    // f32 -> bf16 conversions
    cvt_bf16_kernel<<<2048, 256, 0, stream>>>(x,    x_bf,    524288);
    cvt_bf16_kernel<<<3072, 256, 0, stream>>>(Wqkv, Wqkv_bf, 786432);
    cvt_bf16_kernel<<<1024, 256, 0, stream>>>(Wcol, Wcol_bf, 262144);
    cvt_bf16_kernel<<<1024, 256, 0, stream>>>(Wout, Wout_bf, 262144);
    // ri = LN(reproject(past_values)) -> bf16
    ln_kernel<<<16384, 256, 0, stream>>>(pv, ri_bf);

    // qkv = x @ Wqkv^T + bqkv
    gemm_bf16_kernel<<<dim3(24, 16), 256, 0, stream>>>(x_bf, Wqkv_bf, bqkv, qkv, 1024, 3072);
    // q_col = x @ Wcol^T + bcol
    gemm_bf16_kernel<<<dim3(8, 16), 256, 0, stream>>>(x_bf, Wcol_bf, bcol, qcolw, 1024, 1024);
    // rkv = ri @ Wqkv[1024:3072]^T + bqkv[1024:3072]
    gemm_bf16_kernel<<<dim3(16, 128), 256, 0, stream>>>(ri_bf, Wqkv_bf + (size_t)1024 * 1024,
                                                        bqkv + 1024, rkv, 1024, 2048);
    // attention -> ctx (bf16)
    attn_kernel<<<dim3(32, 16), 256, 0, stream>>>(qkv, qcolw, rkv, ctx_bf);
    // out = ctx @ Wout^T + bout
    gemm_bf16_kernel<<<dim3(8, 16), 256, 0, stream>>>(ctx_bf, Wout_bf, bout, out, 1024, 1024);
}

// Round 3
// 395.090 us; speedup vs baseline: 4.4551x; 1.5467x over previous
//
#include <hip/hip_runtime.h>
#include <math.h>

#define D   1024
#define H   16
#define HD  64
#define SEQ 2048
#define LL  8
#define QKV_LD 3072
#define SCALE 0.125f

typedef __attribute__((ext_vector_type(8))) __bf16 bf16x8;
typedef __attribute__((ext_vector_type(4))) float floatx4;
typedef __attribute__((ext_vector_type(8))) unsigned short ushort8;

__device__ inline unsigned short f32_to_bf16(float f) {
    unsigned int u = __builtin_bit_cast(unsigned int, f);
    u += 0x7FFF + ((u >> 16) & 1);   // round-to-nearest-even
    return (unsigned short)(u >> 16);
}
__device__ inline float bf2f(unsigned short u) {
    unsigned int x = (unsigned int)u << 16;
    return __builtin_bit_cast(float, x);
}
__device__ inline void load_lds16(const void* g, void* l) {
    __builtin_amdgcn_global_load_lds(
        (__attribute__((address_space(1))) void*)g,
        (__attribute__((address_space(3))) void*)l, 16, 0, 0);
}

// ---------------------------------------------------------------------------
// f32 -> bf16 convert
// ---------------------------------------------------------------------------
__global__ __launch_bounds__(256) void cvt_bf16_kernel(
    const float* __restrict__ in, unsigned short* __restrict__ out, int n4)
{
    int i = blockIdx.x * 256 + threadIdx.x;
    if (i < n4) {
        float4 v = ((const float4*)in)[i];
        ushort4 o;
        o.x = f32_to_bf16(v.x); o.y = f32_to_bf16(v.y);
        o.z = f32_to_bf16(v.z); o.w = f32_to_bf16(v.w);
        ((ushort4*)out)[i] = o;
    }
}

// ---------------------------------------------------------------------------
// bf16 MFMA GEMM: C[M,N] = A[M,K] @ W[N,K]^T + bias[N]. CT = float or ushort.
// 128x128 tile, BK=32, 4 waves, 4x4 16x16x32 MFMAs per wave.
// ---------------------------------------------------------------------------
template <typename CT>
__global__ __launch_bounds__(256) void gemm_bf16_kernel(
    const unsigned short* __restrict__ A, const unsigned short* __restrict__ W,
    const float* __restrict__ bias, CT* __restrict__ C, int K, int N)
{
    __shared__ unsigned short As[128 * 32];
    __shared__ unsigned short Ws[128 * 32];
    const int t    = threadIdx.x;
    const int wave = t >> 6, lane = t & 63;
    const int wm   = wave >> 1, wn = wave & 1;
    const int m0   = blockIdx.y * 128, n0 = blockIdx.x * 128;

    floatx4 acc[4][4];
#pragma unroll
    for (int i = 0; i < 4; i++)
#pragma unroll
        for (int j = 0; j < 4; j++) acc[i][j] = (floatx4)0.f;

    const int lrow = lane >> 2;
    const int lcol = (lane & 3) * 8;
    const unsigned short* Ag = A + (size_t)(m0 + wave * 32 + lrow) * K + lcol;
    const unsigned short* Wg = W + (size_t)(n0 + wave * 32 + lrow) * K + lcol;
    unsigned short* Asw = &As[wave * 32 * 32];
    unsigned short* Wsw = &Ws[wave * 32 * 32];
    const size_t rowskip = (size_t)16 * K;

    const int arow  = lane & 15;
    const int aquad = (lane >> 4) * 8;

    for (int k0 = 0; k0 < K; k0 += 32) {
        load_lds16(Ag + k0,           Asw);
        load_lds16(Ag + k0 + rowskip, Asw + 16 * 32);
        load_lds16(Wg + k0,           Wsw);
        load_lds16(Wg + k0 + rowskip, Wsw + 16 * 32);
        __syncthreads();

        bf16x8 af[4], wf[4];
#pragma unroll
        for (int mi = 0; mi < 4; mi++)
            af[mi] = *(const bf16x8*)&As[(wm * 64 + mi * 16 + arow) * 32 + aquad];
#pragma unroll
        for (int ni = 0; ni < 4; ni++)
            wf[ni] = *(const bf16x8*)&Ws[(wn * 64 + ni * 16 + arow) * 32 + aquad];
#pragma unroll
        for (int mi = 0; mi < 4; mi++)
#pragma unroll
            for (int ni = 0; ni < 4; ni++)
                acc[mi][ni] = __builtin_amdgcn_mfma_f32_16x16x32_bf16(
                    af[mi], wf[ni], acc[mi][ni], 0, 0, 0);
        __syncthreads();
    }

    const int crow = (lane >> 4) * 4, ccol = lane & 15;
#pragma unroll
    for (int mi = 0; mi < 4; mi++) {
#pragma unroll
        for (int ni = 0; ni < 4; ni++) {
            const int gm = m0 + wm * 64 + mi * 16 + crow;
            const int gn = n0 + wn * 64 + ni * 16 + ccol;
            const float bb = bias[gn];
#pragma unroll
            for (int r = 0; r < 4; r++) {
                float v = acc[mi][ni][r] + bb;
                if constexpr (sizeof(CT) == 2)
                    C[(size_t)(gm + r) * N + gn] = (CT)f32_to_bf16(v);
                else
                    C[(size_t)(gm + r) * N + gn] = v;
            }
        }
    }
}

// ---------------------------------------------------------------------------
// LayerNorm of reprojected past_values -> bf16.
// ---------------------------------------------------------------------------
__global__ __launch_bounds__(256) void ln_kernel(
    const float* __restrict__ pv, unsigned short* __restrict__ ri)
{
    const int r = blockIdx.x;
    const int s = r >> 3, l = r & 7;
    const int t = threadIdx.x;
    const int h = t >> 4, e = (t & 15) * 4;
    const size_t src = (size_t)l * (H * SEQ * HD) + (size_t)h * (SEQ * HD)
                     + (size_t)s * HD + e;
    float4 v = *(const float4*)(pv + src);
    float sum = v.x + v.y + v.z + v.w;
    float sq  = v.x * v.x + v.y * v.y + v.z * v.z + v.w * v.w;
#pragma unroll
    for (int off = 32; off; off >>= 1) {
        sum += __shfl_xor(sum, off);
        sq  += __shfl_xor(sq, off);
    }
    __shared__ float red[8];
    if ((t & 63) == 0) { red[(t >> 6) * 2] = sum; red[(t >> 6) * 2 + 1] = sq; }
    __syncthreads();
    sum = red[0] + red[2] + red[4] + red[6];
    sq  = red[1] + red[3] + red[5] + red[7];
    const float mean = sum * (1.f / 1024.f);
    const float var  = sq * (1.f / 1024.f) - mean * mean;
    const float rstd = rsqrtf(var + 1e-5f);
    ushort4 o;
    o.x = f32_to_bf16((v.x - mean) * rstd);
    o.y = f32_to_bf16((v.y - mean) * rstd);
    o.z = f32_to_bf16((v.z - mean) * rstd);
    o.w = f32_to_bf16((v.w - mean) * rstd);
    *(ushort4*)(ri + (size_t)r * D + t * 4) = o;
}

// ---------------------------------------------------------------------------
// MFMA flash dual attention. Block = (head, 64-query tile), 4 waves.
// Wave w owns queries [w*16, w*16+16). QK^T and PV via 16x16x32 bf16 MFMA.
// P converts C-layout -> A-layout through padded LDS (f32).
// Memory keys (8/query from rkv) folded into softmax in the epilogue.
// LDS padding: bf16 tiles stride 72 (+8), f32 P stride 68 (+4): all fragment
// reads/writes are <=2-way bank aliased (free).
// ---------------------------------------------------------------------------
__global__ __launch_bounds__(256) void attn_mfma_kernel(
    const unsigned short* __restrict__ qkv, const unsigned short* __restrict__ qcol,
    const unsigned short* __restrict__ rkv, unsigned short* __restrict__ ctx)
{
    const int t    = threadIdx.x;
    const int w    = t >> 6, lane = t & 63;
    const int lrow = lane & 15;          // fragment m/n index
    const int lk   = (lane >> 4) * 8;    // fragment k offset
    const int rrow = (lane >> 4) * 4;    // C/D row base
    const int h    = blockIdx.y;
    const int bx   = blockIdx.x;
    // heavy/light interleave: even bx -> qt=bx/2 (light), odd -> 31-bx/2 (heavy)
    const int qt   = (bx & 1) ? (31 - (bx >> 1)) : (bx >> 1);
    const int q0   = qt * 64;

    __shared__ unsigned short Qs[64 * 72];
    __shared__ unsigned short Ks[64 * 72];
    __shared__ unsigned short Vt[64 * 72];   // transposed: [e][key]
    __shared__ float Ps[64 * 68];            // P, later reused as O
    __shared__ float row_m[64], row_l[64];
    __shared__ float mem_alpha[64], mem_suml[64], mem_p[64 * 8];

    // stage Q [q][e]
#pragma unroll
    for (int p = 0; p < 2; p++) {
        int idx = p * 256 + t;
        int row = idx >> 3, col = (idx & 7) * 8;
        *(bf16x8*)&Qs[row * 72 + col] =
            *(const bf16x8*)(qkv + (size_t)(q0 + row) * QKV_LD + h * HD + col);
    }

    float m_i[4], l_i[4];
    floatx4 Oacc[4];
#pragma unroll
    for (int r = 0; r < 4; r++) { m_i[r] = -1e30f; l_i[r] = 0.f; }
#pragma unroll
    for (int et = 0; et < 4; et++) Oacc[et] = (floatx4)0.f;

    for (int jt = 0; jt <= qt; jt++) {
        const int j0 = jt * 64;
        // stage K [key][e]
#pragma unroll
        for (int p = 0; p < 2; p++) {
            int idx = p * 256 + t;
            int row = idx >> 3, col = (idx & 7) * 8;
            *(bf16x8*)&Ks[row * 72 + col] =
                *(const bf16x8*)(qkv + (size_t)(j0 + row) * QKV_LD + D + h * HD + col);
        }
        // stage V transposed -> Vt[e][key] (pack key pairs into b32 writes)
        {
            const int pr = t & 31, eg = t >> 5;
            const unsigned short* v0 =
                qkv + (size_t)(j0 + 2 * pr) * QKV_LD + 2 * D + h * HD + eg * 8;
            ushort8 a = *(const ushort8*)v0;
            ushort8 b = *(const ushort8*)(v0 + QKV_LD);
#pragma unroll
            for (int j = 0; j < 8; j++) {
                unsigned int pk = (unsigned int)a[j] | ((unsigned int)b[j] << 16);
                *(unsigned int*)&Vt[(eg * 8 + j) * 72 + 2 * pr] = pk;
            }
        }
        __syncthreads();

        // S = Q K^T (f32 accum)
        floatx4 S[4];
#pragma unroll
        for (int nt = 0; nt < 4; nt++) S[nt] = (floatx4)0.f;
#pragma unroll
        for (int kst = 0; kst < 2; kst++) {
            bf16x8 aq = *(const bf16x8*)&Qs[(w * 16 + lrow) * 72 + kst * 32 + lk];
#pragma unroll
            for (int nt = 0; nt < 4; nt++) {
                bf16x8 bk = *(const bf16x8*)&Ks[(nt * 16 + lrow) * 72 + kst * 32 + lk];
                S[nt] = __builtin_amdgcn_mfma_f32_16x16x32_bf16(aq, bk, S[nt], 0, 0, 0);
            }
        }

        // online softmax on C-layout rows
#pragma unroll
        for (int r = 0; r < 4; r++) {
            const int qg = q0 + w * 16 + rrow + r;
            float sc[4];
            float mx = -1e30f;
#pragma unroll
            for (int nt = 0; nt < 4; nt++) {
                sc[nt] = S[nt][r] * SCALE;
                if (j0 + nt * 16 + lrow > qg) sc[nt] = -1e30f;
                mx = fmaxf(mx, sc[nt]);
            }
#pragma unroll
            for (int off = 1; off < 16; off <<= 1)
                mx = fmaxf(mx, __shfl_xor(mx, off));
            const float newm  = fmaxf(m_i[r], mx);
            const float alpha = __expf(m_i[r] - newm);
            m_i[r] = newm;
            float ps = 0.f;
#pragma unroll
            for (int nt = 0; nt < 4; nt++) {
                float pe = __expf(sc[nt] - newm);
                ps += pe;
                Ps[(w * 16 + rrow + r) * 68 + nt * 16 + lrow] = pe;
            }
#pragma unroll
            for (int off = 1; off < 16; off <<= 1)
                ps += __shfl_xor(ps, off);
            l_i[r] = l_i[r] * alpha + ps;
#pragma unroll
            for (int et = 0; et < 4; et++) Oacc[et][r] *= alpha;
        }

        // O += P @ V   (A from own Ps rows; B from shared Vt)
#pragma unroll
        for (int kst = 0; kst < 2; kst++) {
            float pf[8];
            *(float4*)&pf[0] = *(const float4*)&Ps[(w * 16 + lrow) * 68 + kst * 32 + lk];
            *(float4*)&pf[4] = *(const float4*)&Ps[(w * 16 + lrow) * 68 + kst * 32 + lk + 4];
            bf16x8 ap;
#pragma unroll
            for (int j = 0; j < 8; j++) ap[j] = (__bf16)pf[j];
#pragma unroll
            for (int et = 0; et < 4; et++) {
                bf16x8 bv = *(const bf16x8*)&Vt[(et * 16 + lrow) * 72 + kst * 32 + lk];
                Oacc[et] = __builtin_amdgcn_mfma_f32_16x16x32_bf16(ap, bv, Oacc[et], 0, 0, 0);
            }
        }
        __syncthreads();
    }

    // ---- spill O, m, l to LDS (Ps reused as O buffer) ----
#pragma unroll
    for (int r = 0; r < 4; r++) {
        const int ql = w * 16 + rrow + r;
        if (lrow == 0) { row_m[ql] = m_i[r]; row_l[ql] = l_i[r]; }
#pragma unroll
        for (int et = 0; et < 4; et++)
            Ps[ql * 68 + et * 16 + lrow] = Oacc[et][r];
    }
    __syncthreads();

    // ---- memory-key scores ----
    {
        const int qi = t >> 2, quad = t & 3;
        const int qg = q0 + qi;
        float qv[16];
        const unsigned short* qcp = qcol + (size_t)qg * D + h * HD + quad * 16;
        ushort8 qa = *(const ushort8*)qcp;
        ushort8 qb = *(const ushort8*)(qcp + 8);
#pragma unroll
        for (int j = 0; j < 8; j++) {
            qv[j]     = bf2f(qa[j]) * SCALE;
            qv[8 + j] = bf2f(qb[j]) * SCALE;
        }
        float ms[8];
#pragma unroll
        for (int l = 0; l < 8; l++) {
            const unsigned short* rr = rkv + (size_t)(qg * LL + l) * 2048 + h * HD + quad * 16;
            ushort8 ra = *(const ushort8*)rr;
            ushort8 rb = *(const ushort8*)(rr + 8);
            float pacc = 0.f;
#pragma unroll
            for (int j = 0; j < 8; j++)
                pacc += qv[j] * bf2f(ra[j]) + qv[8 + j] * bf2f(rb[j]);
            pacc += __shfl_xor(pacc, 1);
            pacc += __shfl_xor(pacc, 2);
            ms[l] = pacc;
        }
        const float mo = row_m[qi];
        float mm = mo;
#pragma unroll
        for (int l = 0; l < 8; l++) mm = fmaxf(mm, ms[l]);
        const float alpha = __expf(mo - mm);
        float suml = 0.f;
        float pl[8];
#pragma unroll
        for (int l = 0; l < 8; l++) { pl[l] = __expf(ms[l] - mm); suml += pl[l]; }
        if (quad == 0) {
            mem_alpha[qi] = alpha;
            mem_suml[qi]  = suml;
#pragma unroll
            for (int l = 0; l < 8; l++) mem_p[qi * 8 + l] = pl[l];
        }
    }
    __syncthreads();

    // ---- combine + write ctx (bf16) ----
    {
        const int tx = t & 15, ty = t >> 4;
#pragma unroll
        for (int i = 0; i < 4; i++) {
            const int qi = ty * 4 + i, qg = q0 + qi;
            const float alpha = mem_alpha[qi];
            const float lf = row_l[qi] * alpha + mem_suml[qi];
            float4 o = *(const float4*)&Ps[qi * 68 + tx * 4];
            o.x *= alpha; o.y *= alpha; o.z *= alpha; o.w *= alpha;
#pragma unroll
            for (int l = 0; l < 8; l++) {
                const float p = mem_p[qi * 8 + l];
                ushort4 vb = *(const ushort4*)(rkv + (size_t)(qg * LL + l) * 2048
                                               + D + h * HD + tx * 4);
                o.x = fmaf(p, bf2f(vb.x), o.x);
                o.y = fmaf(p, bf2f(vb.y), o.y);
                o.z = fmaf(p, bf2f(vb.z), o.z);
                o.w = fmaf(p, bf2f(vb.w), o.w);
            }
            const float rr = 1.f / lf;
            ushort4 ob;
            ob.x = f32_to_bf16(o.x * rr); ob.y = f32_to_bf16(o.y * rr);
            ob.z = f32_to_bf16(o.z * rr); ob.w = f32_to_bf16(o.w * rr);
            *(ushort4*)(ctx + (size_t)qg * D + h * HD + tx * 4) = ob;
        }
    }
}

// ---------------------------------------------------------------------------
extern "C" void kernel_launch(void* const* d_in, const int* in_sizes, int n_in,
                              void* d_out, int out_size, void* d_ws, size_t ws_size,
                              hipStream_t stream)
{
    const float* x    = (const float*)d_in[0];
    const float* pv   = (const float*)d_in[1];
    const float* Wqkv = (const float*)d_in[2];
    const float* bqkv = (const float*)d_in[3];
    const float* Wcol = (const float*)d_in[4];
    const float* bcol = (const float*)d_in[5];
    const float* Wout = (const float*)d_in[6];
    const float* bout = (const float*)d_in[7];
    float* out = (float*)d_out;

    char* p = (char*)d_ws;
    unsigned short* x_bf    = (unsigned short*)p; p += (size_t)2048 * 1024 * 2;
    unsigned short* Wqkv_bf = (unsigned short*)p; p += (size_t)3072 * 1024 * 2;
    unsigned short* Wcol_bf = (unsigned short*)p; p += (size_t)1024 * 1024 * 2;
    unsigned short* Wout_bf = (unsigned short*)p; p += (size_t)1024 * 1024 * 2;
    unsigned short* ri_bf   = (unsigned short*)p; p += (size_t)16384 * 1024 * 2;
    unsigned short* qkv_bf  = (unsigned short*)p; p += (size_t)2048 * 3072 * 2;
    unsigned short* qcol_bf = (unsigned short*)p; p += (size_t)2048 * 1024 * 2;
    unsigned short* rkv_bf  = (unsigned short*)p; p += (size_t)16384 * 2048 * 2;
    unsigned short* ctx_bf  = (unsigned short*)p; p += (size_t)2048 * 1024 * 2;
    // ~136.5 MB total

    cvt_bf16_kernel<<<2048, 256, 0, stream>>>(x,    x_bf,    524288);
    cvt_bf16_kernel<<<3072, 256, 0, stream>>>(Wqkv, Wqkv_bf, 786432);
    cvt_bf16_kernel<<<1024, 256, 0, stream>>>(Wcol, Wcol_bf, 262144);
    cvt_bf16_kernel<<<1024, 256, 0, stream>>>(Wout, Wout_bf, 262144);
    ln_kernel<<<16384, 256, 0, stream>>>(pv, ri_bf);

    // qkv = x @ Wqkv^T + bqkv  (bf16 out)
    gemm_bf16_kernel<unsigned short><<<dim3(24, 16), 256, 0, stream>>>(
        x_bf, Wqkv_bf, bqkv, qkv_bf, 1024, 3072);
    // q_col = x @ Wcol^T + bcol  (bf16 out)
    gemm_bf16_kernel<unsigned short><<<dim3(8, 16), 256, 0, stream>>>(
        x_bf, Wcol_bf, bcol, qcol_bf, 1024, 1024);
    // rkv = ri @ Wqkv[1024:3072]^T + bqkv[1024:3072]  (bf16 out)
    gemm_bf16_kernel<unsigned short><<<dim3(16, 128), 256, 0, stream>>>(
        ri_bf, Wqkv_bf + (size_t)1024 * 1024, bqkv + 1024, rkv_bf, 1024, 2048);
    // attention -> ctx (bf16)
    attn_mfma_kernel<<<dim3(32, 16), 256, 0, stream>>>(qkv_bf, qcol_bf, rkv_bf, ctx_bf);
    // out = ctx @ Wout^T + bout  (f32 out)
    gemm_bf16_kernel<float><<<dim3(8, 16), 256, 0, stream>>>(
        ctx_bf, Wout_bf, bout, out, 1024, 1024);
}